// Round 1
// baseline (268.924 us; speedup 1.0000x reference)
//
#include <hip/hip_runtime.h>

// SparseDIA (9 static offsets) @ dense:  out[r,c] = sum_k diags[k, r+off] * other[r+off, c]
// N=8192 rows, M=4096 cols, fp32. Memory-bound (ideal ~268 MB HBM traffic).

#define DIA_N 8192
#define DIA_M 4096
#define M4 (DIA_M / 4)   // float4 columns per row = 1024

__global__ __launch_bounds__(256) void sparse_dia_kernel(
    const float* __restrict__ diags,   // [9, N]
    const float* __restrict__ other,   // [N, M]
    float* __restrict__ out)           // [N, M]
{
    constexpr int OFF[9] = {-128, -64, -8, -1, 0, 1, 8, 64, 128};

    const int r  = blockIdx.y;                                // output row (block-uniform)
    const int c4 = blockIdx.x * blockDim.x + threadIdx.x;     // float4 column index

    const float4* __restrict__ o4 = (const float4*)other;
    float4* __restrict__ out4     = (float4*)out;

    float4 acc = make_float4(0.f, 0.f, 0.f, 0.f);

    if (r >= 128 && r < DIA_N - 128) {
        // Fast path: all 9 offsets in range, no per-lane branching.
#pragma unroll
        for (int k = 0; k < 9; ++k) {
            const int q = r + OFF[k];
            const float d = diags[k * DIA_N + q];   // block-uniform -> scalar load
            const float4 v = o4[q * M4 + c4];
            acc.x += d * v.x;
            acc.y += d * v.y;
            acc.z += d * v.z;
            acc.w += d * v.w;
        }
    } else {
        // Edge rows (first/last 128): guard each offset. Branches are
        // block-uniform (r uniform), so no wave divergence.
#pragma unroll
        for (int k = 0; k < 9; ++k) {
            const int q = r + OFF[k];
            if (q >= 0 && q < DIA_N) {
                const float d = diags[k * DIA_N + q];
                const float4 v = o4[q * M4 + c4];
                acc.x += d * v.x;
                acc.y += d * v.y;
                acc.z += d * v.z;
                acc.w += d * v.w;
            }
        }
    }

    out4[r * M4 + c4] = acc;
}

extern "C" void kernel_launch(void* const* d_in, const int* in_sizes, int n_in,
                              void* d_out, int out_size, void* d_ws, size_t ws_size,
                              hipStream_t stream) {
    const float* diags = (const float*)d_in[0];   // 9 * 8192 fp32
    const float* other = (const float*)d_in[1];   // 8192 * 4096 fp32
    float* out         = (float*)d_out;           // 8192 * 4096 fp32

    // 256 threads = 256 float4 columns per block; M4=1024 -> grid.x=4; grid.y=N rows.
    dim3 block(256, 1, 1);
    dim3 grid(M4 / 256, DIA_N, 1);
    sparse_dia_kernel<<<grid, block, 0, stream>>>(diags, other, out);
}